// Round 7
// baseline (214.642 us; speedup 1.0000x reference)
//
#include <hip/hip_runtime.h>
#include <math.h>

// Problem constants (match reference)
namespace {
constexpr int kB = 2048;
constexpr int kC = 32000;
constexpr int kThreads = 256;
constexpr float kInvT = 0.05f;   // 1 / T_KD (T_KD = 20)
constexpr int kSlotBase = 16;    // floats; ws[0] = ticket counter
constexpr int kSlot = 12;        // floats per row slot
}

// Native clang vector type — __builtin_nontemporal_load requires a pointer
// to integer/float/pointer or a VECTOR of such types.
typedef float floatx4 __attribute__((ext_vector_type(4)));

// Non-temporal float4 load: nt-flagged global_load_dwordx4 (evict-first /
// stream through caches) for the two teacher arrays; the student array
// stays cache-resident across timed replays.
__device__ __forceinline__ floatx4 ntload(const float* p) {
    return __builtin_nontemporal_load(reinterpret_cast<const floatx4*>(p));
}

// One block per row, fully fused:
//  - single fused pass over the row (depth-1 ping-pong pipeline, nt teacher
//    streams), as in round 6;
//  - per-row results written to a ws slot;
//  - rocPRIM-style "last block" ticket: the block drawing ticket kB-1 reduces
//    all slots (global max + weighted loss mean) and writes out[0].
// Ticket counter (ws[0]) is zeroed by a hipMemsetAsync node each call.
__global__ __launch_bounds__(kThreads) void mt2_fused(
    const float* __restrict__ o1, const float* __restrict__ o2,
    const float* __restrict__ os, const int* __restrict__ tgt,
    float* __restrict__ ws, float* __restrict__ out)
{
    const int tid = threadIdx.x;
    const int row = blockIdx.x;
    const size_t base = (size_t)row * kC;
    const float* r1 = o1 + base;
    const float* r2 = o2 + base;
    const floatx4* ps = reinterpret_cast<const floatx4*>(os + base);

    float t1a = -INFINITY, t2a = -INFINITY, Za = 0.f, Sa = 0.f;
    float t1b = -INFINITY, t2b = -INFINITY, Zb = 0.f, Sb = 0.f;
    float t1c = -INFINITY, t2c = -INFINITY, Zc = 0.f, Sc = 0.f;
    float Z1 = 0.f, Z20 = 0.f;

    auto process = [&](floatx4 v1, floatx4 v2, floatx4 vs) {
        #pragma unroll
        for (int k = 0; k < 4; ++k) {
            float x1 = v1[k], x2 = v2[k], s = vs[k];
            float xm = 0.5f * (x1 + x2);
            float o;
            o = t1a; t1a = fmaxf(o, x1); t2a = fmaxf(t2a, fminf(o, x1));
            o = t1b; t1b = fmaxf(o, x2); t2b = fmaxf(t2b, fminf(o, x2));
            o = t1c; t1c = fmaxf(o, xm); t2c = fmaxf(t2c, fminf(o, xm));
            float e1 = __expf(x1 * kInvT);
            float e2 = __expf(x2 * kInvT);
            float em = __expf(xm * kInvT);
            Za += e1; Sa = __fmaf_rn(e1, s, Sa);
            Zb += e2; Sb = __fmaf_rn(e2, s, Sb);
            Zc += em; Sc = __fmaf_rn(em, s, Sc);
            Z1  += __expf(s);
            Z20 += __expf(s * kInvT);
        }
    };

    // 8000 float4 chunks = 31 full 256-strided chunks + 64-wide tail.
    floatx4 a1, a2, asv, b1, b2, bsv;
    {   // prologue: chunk 0 -> A
        const int i0 = tid;
        a1 = ntload(r1 + 4 * i0); a2 = ntload(r2 + 4 * i0); asv = ps[i0];
    }
    #pragma unroll 1
    for (int j = 0; j < 30; j += 2) {
        {   // load chunk j+1 -> B, pinned above process(A)
            const int i1 = tid + (j + 1) * 256;
            b1 = ntload(r1 + 4 * i1); b2 = ntload(r2 + 4 * i1); bsv = ps[i1];
        }
        __builtin_amdgcn_sched_barrier(0);
        process(a1, a2, asv);                 // chunk j
        {   // load chunk j+2 -> A, pinned above process(B)
            const int i2 = tid + (j + 2) * 256;
            a1 = ntload(r1 + 4 * i2); a2 = ntload(r2 + 4 * i2); asv = ps[i2];
        }
        __builtin_amdgcn_sched_barrier(0);
        process(b1, b2, bsv);                 // chunk j+1
    }
    process(a1, a2, asv);                     // chunk 30
    if (tid < 64) {                           // tail: elements 31744..31999
        const int i = 7936 + tid;
        process(ntload(r1 + 4 * i), ntload(r2 + 4 * i), ps[i]);
    }

    // 64-lane butterfly reduce
    #pragma unroll
    for (int m = 32; m >= 1; m >>= 1) {
        float u1, u2;
        u1 = __shfl_xor(t1a, m); u2 = __shfl_xor(t2a, m);
        t2a = fmaxf(fmaxf(t2a, u2), fminf(t1a, u1)); t1a = fmaxf(t1a, u1);
        u1 = __shfl_xor(t1b, m); u2 = __shfl_xor(t2b, m);
        t2b = fmaxf(fmaxf(t2b, u2), fminf(t1b, u1)); t1b = fmaxf(t1b, u1);
        u1 = __shfl_xor(t1c, m); u2 = __shfl_xor(t2c, m);
        t2c = fmaxf(fmaxf(t2c, u2), fminf(t1c, u1)); t1c = fmaxf(t1c, u1);
        Za  += __shfl_xor(Za, m);  Sa  += __shfl_xor(Sa, m);
        Zb  += __shfl_xor(Zb, m);  Sb  += __shfl_xor(Sb, m);
        Zc  += __shfl_xor(Zc, m);  Sc  += __shfl_xor(Sc, m);
        Z1  += __shfl_xor(Z1, m);  Z20 += __shfl_xor(Z20, m);
    }

    // cross-wave merge via LDS (4 waves)
    __shared__ float red[4][14];
    const int wid = tid >> 6;
    if ((tid & 63) == 0) {
        float* r = red[wid];
        r[0] = t1a; r[1] = t2a; r[2]  = Za; r[3]  = Sa;
        r[4] = t1b; r[5] = t2b; r[6]  = Zb; r[7]  = Sb;
        r[8] = t1c; r[9] = t2c; r[10] = Zc; r[11] = Sc;
        r[12] = Z1; r[13] = Z20;
    }
    __syncthreads();
    __shared__ unsigned sIsLast;
    if (tid == 0) {
        for (int w = 1; w < 4; ++w) {
            const float* r = red[w];
            t2a = fmaxf(fmaxf(t2a, r[1]), fminf(t1a, r[0])); t1a = fmaxf(t1a, r[0]);
            Za += r[2]; Sa += r[3];
            t2b = fmaxf(fmaxf(t2b, r[5]), fminf(t1b, r[4])); t1b = fmaxf(t1b, r[4]);
            Zb += r[6]; Sb += r[7];
            t2c = fmaxf(fmaxf(t2c, r[9]), fminf(t1c, r[8])); t1c = fmaxf(t1c, r[8]);
            Zc += r[10]; Sc += r[11];
            Z1 += r[12]; Z20 += r[13];
        }
        const int t = tgt[row];
        const float o1t = o1[base + t];
        const float o2t = o2[base + t];
        const float st  = os[base + t];
        const float omt = 0.5f * (o1t + o2t);   // same expression as xm -> bit-equal
        float d0 = (o1t == t1a) ? (t1a - t2a) : 0.f;
        float d1 = (o2t == t1b) ? (t1b - t2b) : 0.f;
        float d2 = (omt == t1c) ? (t1c - t2c) : 0.f;
        // softmax(d / 2)
        float h0 = 0.5f * d0, h1 = 0.5f * d1, h2 = 0.5f * d2;
        float hm = fmaxf(h0, fmaxf(h1, h2));
        float e0 = __expf(h0 - hm), e1 = __expf(h1 - hm), e2 = __expf(h2 - hm);
        float inv = 1.f / (e0 + e1 + e2);
        float CE   = logf(Z1) - st;          // lse(s) - s_tgt
        float lseu = logf(Z20);              // lse(s/20)
        float* slot = ws + kSlotBase + row * kSlot;
        slot[0] = e0 * inv; slot[1] = e1 * inv; slot[2] = e2 * inv;
        slot[3] = CE;
        slot[4] = 400.f * lseu - 20.f * Sa / Za;
        slot[5] = 400.f * lseu - 20.f * Sb / Zb;
        slot[6] = 400.f * lseu - 20.f * Sc / Zc;
        slot[7] = o1t; slot[8] = o2t; slot[9] = omt;
        slot[10] = fmaxf(t1a, t1b);          // row max over both teachers
        __threadfence();                     // release: slot visible device-wide
        unsigned old = atomicAdd(reinterpret_cast<unsigned*>(ws), 1u);
        sIsLast = (old == (unsigned)(kB - 1)) ? 1u : 0u;
    }
    __syncthreads();
    if (sIsLast == 0u) return;

    // ---- last block: global max + weighted loss mean over all rows ----
    __threadfence();                          // acquire: see all slots
    float m = -INFINITY;
    for (int r = tid; r < kB; r += kThreads)
        m = fmaxf(m, ws[kSlotBase + r * kSlot + 10]);
    #pragma unroll
    for (int x = 32; x >= 1; x >>= 1) m = fmaxf(m, __shfl_xor(m, x));
    __shared__ float smax[4];
    if ((tid & 63) == 0) smax[wid] = m;
    __syncthreads();
    const float maxp = fmaxf(fmaxf(smax[0], smax[1]), fmaxf(smax[2], smax[3]));

    double sum = 0.0;
    for (int r = tid; r < kB; r += kThreads) {
        const float* s = ws + kSlotBase + r * kSlot;
        float CE = s[3];
        float loss = 0.f;
        #pragma unroll
        for (int i = 0; i < 3; ++i) {
            float w8 = 0.8f * (s[7 + i] / maxp);
            loss += s[i] * ((1.f - w8) * CE + w8 * s[4 + i]);
        }
        sum += (double)loss;
    }
    #pragma unroll
    for (int x = 32; x >= 1; x >>= 1) sum += __shfl_xor(sum, x);
    __shared__ double sred[4];
    if ((tid & 63) == 0) sred[wid] = sum;
    __syncthreads();
    if (tid == 0)
        out[0] = (float)((sred[0] + sred[1] + sred[2] + sred[3]) / (double)kB);
}

extern "C" void kernel_launch(void* const* d_in, const int* in_sizes, int n_in,
                              void* d_out, int out_size, void* d_ws, size_t ws_size,
                              hipStream_t stream) {
    const float* o1 = (const float*)d_in[0];
    const float* o2 = (const float*)d_in[1];
    const float* os = (const float*)d_in[2];
    const int*   tg = (const int*)d_in[3];
    float* ws  = (float*)d_ws;
    float* out = (float*)d_out;

    // Zero the ticket counter (ws[0]) each call — graph-legal memset node.
    hipMemsetAsync(d_ws, 0, 4, stream);
    hipLaunchKernelGGL(mt2_fused, dim3(kB), dim3(kThreads), 0, stream,
                       o1, o2, os, tg, ws, out);
}

// Round 8
// 126.295 us; speedup vs baseline: 1.6995x; 1.6995x over previous
//
#include <hip/hip_runtime.h>
#include <math.h>

// Problem constants (match reference)
namespace {
constexpr int kB = 2048;
constexpr int kC = 32000;
constexpr int kNV = kC / 4;      // float4 chunks per row = 8000
constexpr int kThreads = 256;
constexpr float kInvT = 0.05f;   // 1 / T_KD (T_KD = 20)
}

// Native clang vector type — __builtin_nontemporal_load requires a pointer
// to integer/float/pointer or a VECTOR of such types.
typedef float floatx4 __attribute__((ext_vector_type(4)));

// Order-preserving float <-> uint encoding for atomicMax on floats.
// ws[0] is zeroed by a hipMemsetAsync node each call; fenc maps all finite
// floats to values > 0 only for positives — 0u is the smallest encoded
// value, so memset-0 == "-inf" seed.
__device__ __forceinline__ unsigned fenc(float f) {
    unsigned u = __float_as_uint(f);
    return (u & 0x80000000u) ? ~u : (u | 0x80000000u);
}
__device__ __forceinline__ float fdec(unsigned u) {
    return (u & 0x80000000u) ? __uint_as_float(u & 0x7fffffffu)
                             : __uint_as_float(~u);
}

// Non-temporal float4 load: nt-flagged global_load_dwordx4 (evict-first /
// stream through caches) for the two teacher arrays; the student array
// stays cache-resident across timed replays.
__device__ __forceinline__ floatx4 ntload(const float* p) {
    return __builtin_nontemporal_load(reinterpret_cast<const floatx4*>(p));
}

// One block per row. Single fused pass, depth-1 ping-pong software pipeline:
// per segment, issue the NEXT chunk's 3 loads, then sched_barrier(0) pins
// them above the CURRENT chunk's compute -> 3 KB/wave stays in flight under
// every compute phase. o1/o2 nt-streamed; out_s normal (caching) loads.
// NOTE (round 7 lesson): NO per-block __threadfence here — on gfx950 an
// agent-scope fence is a full L2 writeback/invalidate; 2048 of them while
// other blocks stream cost +85 us. Cross-kernel visibility is free.
__global__ __launch_bounds__(kThreads) void mt2_rows(
    const float* __restrict__ o1, const float* __restrict__ o2,
    const float* __restrict__ os, const int* __restrict__ tgt,
    float* __restrict__ ws)
{
    const int tid = threadIdx.x;
    const int row = blockIdx.x;
    const size_t base = (size_t)row * kC;
    const float* r1 = o1 + base;
    const float* r2 = o2 + base;
    const floatx4* ps = reinterpret_cast<const floatx4*>(os + base);

    float t1a = -INFINITY, t2a = -INFINITY, Za = 0.f, Sa = 0.f;
    float t1b = -INFINITY, t2b = -INFINITY, Zb = 0.f, Sb = 0.f;
    float t1c = -INFINITY, t2c = -INFINITY, Zc = 0.f, Sc = 0.f;
    float Z1 = 0.f, Z20 = 0.f;

    auto process = [&](floatx4 v1, floatx4 v2, floatx4 vs) {
        #pragma unroll
        for (int k = 0; k < 4; ++k) {
            float x1 = v1[k], x2 = v2[k], s = vs[k];
            float xm = 0.5f * (x1 + x2);
            float o;
            o = t1a; t1a = fmaxf(o, x1); t2a = fmaxf(t2a, fminf(o, x1));
            o = t1b; t1b = fmaxf(o, x2); t2b = fmaxf(t2b, fminf(o, x2));
            o = t1c; t1c = fmaxf(o, xm); t2c = fmaxf(t2c, fminf(o, xm));
            float e1 = __expf(x1 * kInvT);
            float e2 = __expf(x2 * kInvT);
            float em = __expf(xm * kInvT);
            Za += e1; Sa = __fmaf_rn(e1, s, Sa);
            Zb += e2; Sb = __fmaf_rn(e2, s, Sb);
            Zc += em; Sc = __fmaf_rn(em, s, Sc);
            Z1  += __expf(s);
            Z20 += __expf(s * kInvT);
        }
    };

    // 8000 float4 chunks = 31 full 256-strided chunks + 64-wide tail.
    floatx4 a1, a2, asv, b1, b2, bsv;
    {   // prologue: chunk 0 -> A
        const int i0 = tid;
        a1 = ntload(r1 + 4 * i0); a2 = ntload(r2 + 4 * i0); asv = ps[i0];
    }
    #pragma unroll 1
    for (int j = 0; j < 30; j += 2) {
        {   // load chunk j+1 -> B, pinned above process(A)
            const int i1 = tid + (j + 1) * 256;
            b1 = ntload(r1 + 4 * i1); b2 = ntload(r2 + 4 * i1); bsv = ps[i1];
        }
        __builtin_amdgcn_sched_barrier(0);
        process(a1, a2, asv);                 // chunk j
        {   // load chunk j+2 -> A, pinned above process(B)
            const int i2 = tid + (j + 2) * 256;
            a1 = ntload(r1 + 4 * i2); a2 = ntload(r2 + 4 * i2); asv = ps[i2];
        }
        __builtin_amdgcn_sched_barrier(0);
        process(b1, b2, bsv);                 // chunk j+1
    }
    process(a1, a2, asv);                     // chunk 30
    if (tid < 64) {                           // tail: elements 31744..31999
        const int i = 7936 + tid;
        process(ntload(r1 + 4 * i), ntload(r2 + 4 * i), ps[i]);
    }

    // 64-lane butterfly reduce
    #pragma unroll
    for (int m = 32; m >= 1; m >>= 1) {
        float u1, u2;
        u1 = __shfl_xor(t1a, m); u2 = __shfl_xor(t2a, m);
        t2a = fmaxf(fmaxf(t2a, u2), fminf(t1a, u1)); t1a = fmaxf(t1a, u1);
        u1 = __shfl_xor(t1b, m); u2 = __shfl_xor(t2b, m);
        t2b = fmaxf(fmaxf(t2b, u2), fminf(t1b, u1)); t1b = fmaxf(t1b, u1);
        u1 = __shfl_xor(t1c, m); u2 = __shfl_xor(t2c, m);
        t2c = fmaxf(fmaxf(t2c, u2), fminf(t1c, u1)); t1c = fmaxf(t1c, u1);
        Za  += __shfl_xor(Za, m);  Sa  += __shfl_xor(Sa, m);
        Zb  += __shfl_xor(Zb, m);  Sb  += __shfl_xor(Sb, m);
        Zc  += __shfl_xor(Zc, m);  Sc  += __shfl_xor(Sc, m);
        Z1  += __shfl_xor(Z1, m);  Z20 += __shfl_xor(Z20, m);
    }

    // cross-wave merge via LDS (4 waves)
    __shared__ float red[4][14];
    const int wid = tid >> 6;
    if ((tid & 63) == 0) {
        float* r = red[wid];
        r[0] = t1a; r[1] = t2a; r[2]  = Za; r[3]  = Sa;
        r[4] = t1b; r[5] = t2b; r[6]  = Zb; r[7]  = Sb;
        r[8] = t1c; r[9] = t2c; r[10] = Zc; r[11] = Sc;
        r[12] = Z1; r[13] = Z20;
    }
    __syncthreads();
    if (tid == 0) {
        for (int w = 1; w < 4; ++w) {
            const float* r = red[w];
            t2a = fmaxf(fmaxf(t2a, r[1]), fminf(t1a, r[0])); t1a = fmaxf(t1a, r[0]);
            Za += r[2]; Sa += r[3];
            t2b = fmaxf(fmaxf(t2b, r[5]), fminf(t1b, r[4])); t1b = fmaxf(t1b, r[4]);
            Zb += r[6]; Sb += r[7];
            t2c = fmaxf(fmaxf(t2c, r[9]), fminf(t1c, r[8])); t1c = fmaxf(t1c, r[8]);
            Zc += r[10]; Sc += r[11];
            Z1 += r[12]; Z20 += r[13];
        }
        const int t = tgt[row];
        const float o1t = o1[base + t];
        const float o2t = o2[base + t];
        const float st  = os[base + t];
        const float omt = 0.5f * (o1t + o2t);   // same expression as xm -> bit-equal
        float d0 = (o1t == t1a) ? (t1a - t2a) : 0.f;
        float d1 = (o2t == t1b) ? (t1b - t2b) : 0.f;
        float d2 = (omt == t1c) ? (t1c - t2c) : 0.f;
        // softmax(d / 2)
        float h0 = 0.5f * d0, h1 = 0.5f * d1, h2 = 0.5f * d2;
        float hm = fmaxf(h0, fmaxf(h1, h2));
        float e0 = __expf(h0 - hm), e1 = __expf(h1 - hm), e2 = __expf(h2 - hm);
        float inv = 1.f / (e0 + e1 + e2);
        float CE   = logf(Z1) - st;          // lse(s) - s_tgt
        float lseu = logf(Z20);              // lse(s/20)
        float KD0 = 400.f * lseu - 20.f * Sa / Za;
        float KD1 = 400.f * lseu - 20.f * Sb / Zb;
        float KD2 = 400.f * lseu - 20.f * Sc / Zc;
        float* slot = ws + 16 + row * 10;
        slot[0] = e0 * inv; slot[1] = e1 * inv; slot[2] = e2 * inv;
        slot[3] = CE;
        slot[4] = KD0; slot[5] = KD1; slot[6] = KD2;
        slot[7] = o1t; slot[8] = o2t; slot[9] = omt;
        atomicMax(reinterpret_cast<unsigned*>(ws), fenc(fmaxf(t1a, t1b)));
    }
}

__global__ __launch_bounds__(256) void mt2_final(const float* __restrict__ ws,
                                                 float* __restrict__ out)
{
    const float maxp = fdec(reinterpret_cast<const unsigned*>(ws)[0]);
    double sum = 0.0;
    for (int r = threadIdx.x; r < kB; r += 256) {
        const float* s = ws + 16 + r * 10;
        float CE = s[3];
        float loss = 0.f;
        #pragma unroll
        for (int i = 0; i < 3; ++i) {
            float w8 = 0.8f * (s[7 + i] / maxp);
            loss += s[i] * ((1.f - w8) * CE + w8 * s[4 + i]);
        }
        sum += (double)loss;
    }
    #pragma unroll
    for (int m = 32; m >= 1; m >>= 1) sum += __shfl_xor(sum, m);
    __shared__ double sred[4];
    if ((threadIdx.x & 63) == 0) sred[threadIdx.x >> 6] = sum;
    __syncthreads();
    if (threadIdx.x == 0)
        out[0] = (float)((sred[0] + sred[1] + sred[2] + sred[3]) / (double)kB);
}

extern "C" void kernel_launch(void* const* d_in, const int* in_sizes, int n_in,
                              void* d_out, int out_size, void* d_ws, size_t ws_size,
                              hipStream_t stream) {
    const float* o1 = (const float*)d_in[0];
    const float* o2 = (const float*)d_in[1];
    const float* os = (const float*)d_in[2];
    const int*   tg = (const int*)d_in[3];
    float* ws  = (float*)d_ws;
    float* out = (float*)d_out;

    // Zero the atomicMax slot (ws[0]) — memset node instead of a kernel
    // launch (0u == smallest fenc-encoded value).
    hipMemsetAsync(d_ws, 0, 4, stream);
    hipLaunchKernelGGL(mt2_rows, dim3(kB), dim3(kThreads), 0, stream,
                       o1, o2, os, tg, ws);
    hipLaunchKernelGGL(mt2_final, dim3(1), dim3(256), 0, stream, ws, out);
}